// Round 13
// baseline (177.297 us; speedup 1.0000x reference)
//
#include <hip/hip_runtime.h>

// ============================================================================
// MotionCompensation on MI355X — round 13.
// r13: conv12 single-phase staging (all 128 ch at once — 16 loads in flight,
// one latency exposure, 2 fewer barriers) with ODD-dword LDS strides:
// sA stride 134 ushort (67 dwords ≡ 3 mod 32), sT1 stride 70 (35 ≡ 3).
// Even-dword strides (72/76) only hit even banks => 8/4-way conflicts.
// Deform/prep unchanged from r12.
// ============================================================================

typedef __attribute__((ext_vector_type(8))) short short8;
typedef __attribute__((ext_vector_type(4))) float float4v;
typedef __attribute__((ext_vector_type(2))) float float2v;

#define MFMA_B16(a, b, c) __builtin_amdgcn_mfma_f32_16x16x32_bf16(a, b, c, 0, 0, 0)

__device__ __forceinline__ ushort f2bf(float f) {          // RNE f32 -> bf16
    union { float f; unsigned u; } v; v.f = f;
    unsigned r = v.u + 0x7FFFu + ((v.u >> 16) & 1u);
    return (ushort)(r >> 16);
}
__device__ __forceinline__ float bf2f(ushort h) {
    union { unsigned u; float f; } v; v.u = ((unsigned)h) << 16;
    return v.f;
}

// weights+offsets for one deformable tap (4 corners)
__device__ __forceinline__ void tap_wo(int gy, int gx, int n,
                                       float ox, float oy, float mzv,
                                       float* W, int* O)
{
    int ky = n / 3, kx = n - ky * 3;
    float pxf = (float)(gy + ky) + ox;
    float pyf = (float)(gx + kx) + oy;
    float fx = floorf(pxf), fy = floorf(pyf);
    float qxl = fminf(fmaxf(fx, 0.f), 127.f);
    float qxr = fminf(fmaxf(fx + 1.f, 0.f), 127.f);
    float qyl = fminf(fmaxf(fy, 0.f), 127.f);
    float qyr = fminf(fmaxf(fy + 1.f, 0.f), 127.f);
    float pxc = fminf(fmaxf(pxf, 0.f), 127.f);
    float pyc = fminf(fmaxf(pyf, 0.f), 127.f);
    float glx = 1.f + (qxl - pxc), grx = 1.f - (qxr - pxc);
    float gly = 1.f + (qyl - pyc), gry = 1.f - (qyr - pyc);
    float mm = 1.f / (1.f + __expf(-mzv));
    W[0] = glx * gly * mm; W[1] = grx * gry * mm;
    W[2] = glx * gry * mm; W[3] = grx * gly * mm;
    int ixl = (int)qxl, ixr = (int)qxr, iyl = (int)qyl, iyr = (int)qyr;
    O[0] = ixl * 128 + iyl; O[1] = ixr * 128 + iyr;
    O[2] = ixl * 128 + iyr; O[3] = ixr * 128 + iyl;
}

// packed-float2 bilinear blend of 4 corner short8s; bf16 pack via v_perm
__device__ __forceinline__ short8 interp4(const float* W, const short8* cv)
{
    union U { short8 s; uint4 u; };
    uint4 c[4];
    #pragma unroll
    for (int j = 0; j < 4; ++j) { U t; t.s = cv[j]; c[j] = t.u; }
    U out;
    #pragma unroll
    for (int p = 0; p < 4; ++p) {       // channel pair p = (2p, 2p+1)
        float2v acc = {0.f, 0.f};
        #pragma unroll
        for (int j = 0; j < 4; ++j) {
            unsigned d = (&c[j].x)[p];
            float2v cc = {__uint_as_float(d << 16),
                          __uint_as_float(d & 0xffff0000u)};
            float2v Wv = {W[j], W[j]};
            acc = __builtin_elementwise_fma(cc, Wv, acc);
        }
        unsigned u0 = __float_as_uint(acc.x), u1 = __float_as_uint(acc.y);
        (&out.u.x)[p] = __builtin_amdgcn_perm(u1, u0, 0x07060302u);  // trunc pack
    }
    return out.s;
}

// ---------------------------------------------------------------------------
// prep: blocks 0..511: anchor NCHW f32 -> grouped bf16 (32 ch per block);
//       blocks 512..799: weight repack into wave-coalesced frag layouts:
//   rw1x[s9][ks4][oc64][kk32]   rw2x[s9][ks2][oc64][kk32]
//   rpwx[g8][ks3][n32][kk32] hi/lo  (k=ks*32+kk; k<72: s=k>>3,ic=k&7; k==72 bias)
//   rcwx[g8][ks3][oc16][kk32]       (k<72: n=k>>3, ic=k&7)
// ---------------------------------------------------------------------------
__global__ __launch_bounds__(256) void prep(
    const float* __restrict__ anchor,
    const float* __restrict__ w1, const float* __restrict__ w2,
    const float* __restrict__ pw, const float* __restrict__ pb,
    const float* __restrict__ mw, const float* __restrict__ mb,
    const float* __restrict__ cw,
    ushort* __restrict__ anc_g,
    ushort* __restrict__ rw1, ushort* __restrict__ rw2,
    ushort* __restrict__ rpwh, ushort* __restrict__ rpwl,
    ushort* __restrict__ rcw)
{
    const int blk = blockIdx.x;
    if (blk < 512) {                       // ---- anchor transform (32 ch/blk)
        int pix = (blk & 63) * 256 + threadIdx.x;
        int b = (blk >> 6) & 3;
        int half = blk >> 8;               // 0: ch 0-31, 1: ch 32-63
        ushort tmp[32];
        #pragma unroll
        for (int ch = 0; ch < 32; ++ch)
            tmp[ch] = f2bf(anchor[(((size_t)(b * 64 + half * 32 + ch)) << 14) + pix]);
        #pragma unroll
        for (int grp = 0; grp < 4; ++grp) {
            short8 v;
            #pragma unroll
            for (int j = 0; j < 8; ++j) v[j] = (short)tmp[grp * 8 + j];
            *(short8*)(anc_g + ((size_t)(b * 8 + half * 4 + grp)) * 131072
                       + (size_t)pix * 8) = v;
        }
        return;
    }
    int i = (blk - 512) * 256 + threadIdx.x;   // ---- repack
    if (i < 73728) {                       // rw1x
        int kk = i & 31, r = i >> 5, oc = r & 63, r2 = r >> 6;
        int ks = r2 & 3, s = r2 >> 2, ic = ks * 32 + kk;
        rw1[i] = f2bf(w1[(oc * 128 + ic) * 9 + s]);
    }
    if (i < 36864) {                       // rw2x
        int kk = i & 31, r = i >> 5, oc = r & 63, r2 = r >> 6;
        int ks = r2 & 1, s = r2 >> 1, ic = ks * 32 + kk;
        rw2[i] = f2bf(w2[(oc * 64 + ic) * 9 + s]);
    }
    if (i < 24576) {                       // rpwx hi/lo
        int kk = i & 31, r = i >> 5, n = r & 31, r2 = r >> 5;
        int ks = r2 % 3, g = r2 / 3, k = ks * 32 + kk;
        float v = 0.f;
        if (k < 72) {
            int s = k >> 3, ic = k & 7;
            if (n < 18)      v = pw[((g * 18 + n) * 8 + ic) * 9 + s];
            else if (n < 27) v = mw[((g * 9 + (n - 18)) * 8 + ic) * 9 + s];
        } else if (k == 72) {
            if (n < 18)      v = pb[g * 18 + n];
            else if (n < 27) v = mb[g * 9 + (n - 18)];
        }
        ushort h = f2bf(v);
        rpwh[i] = h;
        rpwl[i] = f2bf(v - bf2f(h));
    }
    if (i < 12288) {                       // rcwx
        int kk = i & 31, r = i >> 5, oc = r & 15, r2 = r >> 4;
        int ks = r2 % 3, g = r2 / 3, k = ks * 32 + kk;
        float v = 0.f;
        if (k < 72 && oc < 8) {
            int n = k >> 3, ic = k & 7;
            v = cw[((g * 8 + oc) * 8 + ic) * 9 + n];
        }
        rcw[i] = f2bf(v);
    }
}

// ---------------------------------------------------------------------------
// Deformable stage (r12). LDS 31,744 B, launch bounds (256,4).
// ---------------------------------------------------------------------------
__global__ __launch_bounds__(256, 4) void deform_mfma(
    const float* __restrict__ o, const ushort* __restrict__ anc_g,
    const ushort* __restrict__ rpwh, const ushort* __restrict__ rpwl,
    const ushort* __restrict__ rcw,
    ushort* __restrict__ xcat_g)
{
    const int tile = blockIdx.x, g = blockIdx.y, b = blockIdx.z;
    const int ty0 = (tile >> 3) * 16, tx0 = (tile & 7) * 16;
    const int tid = threadIdx.x, lane = tid & 63, wave = tid >> 6;
    const int l15 = lane & 15, quad = lane >> 4;

    __shared__ __align__(16) ushort sU[15872];        // 31,744 B
    ushort* slabh = sU;                               // [0, 5184)
    ushort* slabl = sU + 2592;                        // [5184, 10368)
    float*  sOff  = (float*)sU;                       // [0, 27648) after barrier 2
    ushort* sEu   = sU + 13824;                       // [27648, 31744)

    const float* obase = o + (((size_t)(b * 64 + g * 8)) << 14);
    #pragma unroll
    for (int pass = 0; pass < 2; ++pass) {
        int pix = tid + pass * 256;
        if (pix < 324) {
            int r = pix / 18, c = pix - r * 18;
            int gy = ty0 + r - 1, gx = tx0 + c - 1;
            short8 vh = {0, 0, 0, 0, 0, 0, 0, 0};
            short8 vl = {0, 0, 0, 0, 0, 0, 0, 0};
            if ((unsigned)gy < 128u && (unsigned)gx < 128u) {
                const float* p0 = obase + (gy << 7) + gx;
                #pragma unroll
                for (int ic = 0; ic < 8; ++ic) {
                    float v = p0[(size_t)ic << 14];
                    ushort h = f2bf(v);
                    vh[ic] = (short)h;
                    vl[ic] = (short)f2bf(v - bf2f(h));
                }
            }
            *(short8*)(&slabh[pix * 8]) = vh;
            *(short8*)(&slabl[pix * 8]) = vl;
        }
    }
    __syncthreads();                                  // barrier 1

    // ---- phase A: offset/mask conv, split-bf16 3-MFMA
    float4v offacc[4][2] = {};
    #pragma unroll
    for (int ks = 0; ks < 3; ++ks) {
        short8 Bh[2], Bl[2];
        #pragma unroll
        for (int nf = 0; nf < 2; ++nf) {
            int off = ((g * 3 + ks) * 32 + nf * 16 + l15) * 32 + quad * 8;
            Bh[nf] = *(const short8*)(rpwh + off);
            Bl[nf] = *(const short8*)(rpwl + off);
        }
        short8 Ah[4], Al[4];
        if (ks < 2) {
            int s = ks * 4 + quad, sy = s / 3, sx = s - sy * 3;
            #pragma unroll
            for (int py = 0; py < 4; ++py) {
                int row = wave * 4 + py;
                int sl = ((row + sy) * 18 + l15 + sx) * 8;
                Ah[py] = *(const short8*)(&slabh[sl]);
                Al[py] = *(const short8*)(&slabl[sl]);
            }
        } else {
            #pragma unroll
            for (int py = 0; py < 4; ++py) {
                short8 zh = {0, 0, 0, 0, 0, 0, 0, 0};
                short8 zl = {0, 0, 0, 0, 0, 0, 0, 0};
                if (quad == 0) {
                    int row = wave * 4 + py;
                    int sl = ((row + 2) * 18 + l15 + 2) * 8;
                    zh = *(const short8*)(&slabh[sl]);
                    zl = *(const short8*)(&slabl[sl]);
                } else if (quad == 1) {
                    zh[0] = (short)0x3F80;
                }
                Ah[py] = zh; Al[py] = zl;
            }
        }
        #pragma unroll
        for (int py = 0; py < 4; ++py)
            #pragma unroll
            for (int nf = 0; nf < 2; ++nf) {
                offacc[py][nf] = MFMA_B16(Ah[py], Bh[nf], offacc[py][nf]);
                offacc[py][nf] = MFMA_B16(Ah[py], Bl[nf], offacc[py][nf]);
                offacc[py][nf] = MFMA_B16(Al[py], Bh[nf], offacc[py][nf]);
            }
    }
    // phase C B-frags (global, L2-hot) — load before the barrier
    short8 Bw[3];
    #pragma unroll
    for (int ks = 0; ks < 3; ++ks)
        Bw[ks] = *(const short8*)(rcw + (((g * 3 + ks) * 16 + l15) * 32 + quad * 8));

    __syncthreads();                                  // barrier 2: slab dead
    // D bounce (pxcol = quad*4+reg, ch = nf*16+l15) -> sOff (own-wave rows)
    #pragma unroll
    for (int py = 0; py < 4; ++py) {
        int p0 = (wave * 4 + py) * 16 + quad * 4;
        #pragma unroll
        for (int nf = 0; nf < 2; ++nf) {
            int ch = nf * 16 + l15;
            if (ch < 27) {
                #pragma unroll
                for (int reg = 0; reg < 4; ++reg)
                    sOff[(p0 + reg) * 27 + ch] = offacc[py][nf][reg];
            }
        }
    }
    // no barrier: everything below touches only this wave's rows

    const ushort* gb = anc_g + ((size_t)(b * 8 + g)) * 131072;
    const int n1 = quad, n2 = quad + 4;
    float4v cacc[4] = {};
    #pragma unroll
    for (int py = 0; py < 4; ++py) {
        int prow = wave * 4 + py;
        int p = prow * 16 + l15;
        int gy = ty0 + prow, gx = tx0 + l15;

        float W[8]; int O[8];
        tap_wo(gy, gx, n1, sOff[p * 27 + n1], sOff[p * 27 + 9 + n1],
               sOff[p * 27 + 18 + n1], &W[0], &O[0]);
        tap_wo(gy, gx, n2, sOff[p * 27 + n2], sOff[p * 27 + 9 + n2],
               sOff[p * 27 + 18 + n2], &W[4], &O[4]);
        short8 cv[8];
        #pragma unroll
        for (int j = 0; j < 8; ++j)
            cv[j] = *(const short8*)(gb + (size_t)O[j] * 8);
        short8 A0 = interp4(&W[0], &cv[0]);
        short8 A1 = interp4(&W[4], &cv[4]);
        short8 A2 = {0, 0, 0, 0, 0, 0, 0, 0};
        if (quad == 0) {
            float W2[4]; int O2[4];
            tap_wo(gy, gx, 8, sOff[p * 27 + 8], sOff[p * 27 + 17],
                   sOff[p * 27 + 26], W2, O2);
            short8 c2[4];
            #pragma unroll
            for (int j = 0; j < 4; ++j)
                c2[j] = *(const short8*)(gb + (size_t)O2[j] * 8);
            A2 = interp4(W2, c2);
        }
        cacc[py] = MFMA_B16(A0, Bw[0], cacc[py]);
        cacc[py] = MFMA_B16(A1, Bw[1], cacc[py]);
        cacc[py] = MFMA_B16(A2, Bw[2], cacc[py]);
    }

    // epilogue bounce (own-wave rows of sEu; no barrier needed)
    #pragma unroll
    for (int py = 0; py < 4; ++py) {
        if (l15 < 8) {
            #pragma unroll
            for (int reg = 0; reg < 4; ++reg)
                sEu[((wave * 4 + py) * 16 + quad * 4 + reg) * 8 + l15] =
                    f2bf(cacc[py][reg]);
        }
    }
    __builtin_amdgcn_s_waitcnt(0);                    // drain own LDS writes
    {
        const int gy = ty0 + (tid >> 4), gx = tx0 + (tid & 15);
        short8 pk = *(const short8*)(&sEu[tid * 8]);
        *(short8*)(xcat_g + ((size_t)(b * 8 + g)) * 131072
                   + (size_t)((gy << 7) + gx) * 8) = pk;
    }
}

// ---------------------------------------------------------------------------
// conv12: fused conv1 (128->64, +b1) and conv2 (64->64, +b2, +residual).
// 16x8 output patch. SINGLE staging phase: all 128 ch of the 12x20 I-region
// at once (16 loads in flight/thread), sA stride 134 ushort (67 dwords, odd).
// conv1 computes t1 on the 18x10 R-region into sT1 (stride 70 = 35 dwords,
// odd) overlaying dead sA; conv2 consumes sT1 and writes d_out.
// ---------------------------------------------------------------------------
__global__ __launch_bounds__(256, 2) void conv12_mfma(
    const ushort* __restrict__ xg, const ushort* __restrict__ ag,
    const ushort* __restrict__ rw1, const float* __restrict__ b1,
    const ushort* __restrict__ rw2, const float* __restrict__ b2,
    float* __restrict__ out)
{
    const int patch = blockIdx.x, b = blockIdx.y;
    const int px0 = (patch & 7) * 16, py0 = (patch >> 3) * 8;
    const int tid = threadIdx.x, lane = tid & 63, wave = tid >> 6;
    const int l15 = lane & 15, quad = lane >> 4;

    __shared__ __align__(16) ushort sA[240 * 134];    // 64,320 B; sT1 overlays

    // ---- stage I-region: 12x20 px, all 128 ch (16 chunks), one shot
    if (tid < 240) {
        int ri = tid / 20, ci = tid - ri * 20;
        int gy = py0 - 2 + ri, gx = px0 - 2 + ci;
        bool in = ((unsigned)gy < 128u) && ((unsigned)gx < 128u);
        size_t poff = (size_t)((gy << 7) + gx) * 8;
        #pragma unroll
        for (int grp = 0; grp < 16; ++grp) {
            const ushort* src = (grp < 8) ? xg : ag;
            short8 v = {0, 0, 0, 0, 0, 0, 0, 0};
            if (in)
                v = *(const short8*)(src + ((size_t)(b * 8 + (grp & 7))) * 131072 + poff);
            *(short8*)(&sA[tid * 134 + grp * 8]) = v;
        }
    }

    // per-lane A-row geometry for conv1 M-tiles t = 3*wave + j
    int base[3];
    #pragma unroll
    for (int j = 0; j < 3; ++j) {
        int q = 48 * wave + 16 * j + l15;
        int qe = q < 180 ? q : 179;
        int r = qe / 18, c = qe - r * 18;
        base[j] = r * 20 + c;                          // I-region linear index
    }
    __syncthreads();

    // ---- conv1: K = 128 in 4 ks chunks of 32
    float4v acc1[3][4] = {};                           // [j][nf]
    #pragma unroll
    for (int ks = 0; ks < 4; ++ks) {
        #pragma unroll
        for (int s = 0; s < 9; ++s) {
            const int ky = s / 3, kx = s - ky * 3;
            short8 Bf[4];
            #pragma unroll
            for (int nf = 0; nf < 4; ++nf)
                Bf[nf] = *(const short8*)(rw1 +
                    (((s * 4 + ks) * 64 + nf * 16 + l15) * 32 + quad * 8));
            #pragma unroll
            for (int j = 0; j < 3; ++j) {
                short8 A = *(const short8*)(&sA[(base[j] + ky * 20 + kx) * 134
                                                + ks * 32 + quad * 8]);
                #pragma unroll
                for (int nf = 0; nf < 4; ++nf)
                    acc1[j][nf] = MFMA_B16(A, Bf[nf], acc1[j][nf]);
            }
        }
    }
    __syncthreads();                                   // sA dead -> sT1 overlay
    ushort* sT1 = sA;                                  // 180 rows x 70 ushort
    #pragma unroll
    for (int j = 0; j < 3; ++j) {
        #pragma unroll
        for (int reg = 0; reg < 4; ++reg) {
            int q = 48 * wave + 16 * j + quad * 4 + reg;
            int r = q / 18, c = q - r * 18;            // R-region coords
            int gy = py0 - 1 + r, gx = px0 - 1 + c;
            bool in = ((unsigned)gy < 128u) && ((unsigned)gx < 128u);
            #pragma unroll
            for (int nf = 0; nf < 4; ++nf) {
                int oc = nf * 16 + l15;
                float v = acc1[j][nf][reg] + b1[oc];
                sT1[q * 70 + oc] = in ? f2bf(v) : (ushort)0;
            }
        }
    }
    __syncthreads();

    // ---- conv2 from sT1; wave w owns oc tile [16w, 16w+16)
    float4v acc2[8] = {};
    #pragma unroll
    for (int ks = 0; ks < 2; ++ks) {
        #pragma unroll
        for (int s = 0; s < 9; ++s) {
            const int ky = s / 3, kx = s - ky * 3;
            short8 Aw = *(const short8*)(rw2 +
                (((s * 2 + ks) * 64 + wave * 16 + l15) * 32 + quad * 8));
            #pragma unroll
            for (int f = 0; f < 8; ++f) {
                int q = (f + ky) * 18 + l15 + kx;
                short8 Bx = *(const short8*)(&sT1[q * 70 + ks * 32 + quad * 8]);
                acc2[f] = MFMA_B16(Aw, Bx, acc2[f]);
            }
        }
    }
    // epilogue: D oc = 16*wave + quad*4+reg, px = (f, l15); +b2 +residual
    #pragma unroll
    for (int f = 0; f < 8; ++f) {
        int gy = py0 + f, gx = px0 + l15;
        int pix = (gy << 7) + gx;
        #pragma unroll
        for (int reg = 0; reg < 4; ++reg) {
            int oc = wave * 16 + quad * 4 + reg;
            float res = bf2f(xg[((size_t)(b * 8 + (oc >> 3))) * 131072
                               + (size_t)pix * 8 + (oc & 7)]);
            out[(((size_t)(b * 64 + oc)) << 14) + pix] = acc2[f][reg] + b2[oc] + res;
        }
    }
}

// ---------------------------------------------------------------------------
extern "C" void kernel_launch(void* const* d_in, const int* in_sizes, int n_in,
                              void* d_out, int out_size, void* d_ws, size_t ws_size,
                              hipStream_t stream) {
    const float* o      = (const float*)d_in[0];
    const float* anchor = (const float*)d_in[1];
    const float* pw     = (const float*)d_in[2];
    const float* pb     = (const float*)d_in[3];
    const float* mw     = (const float*)d_in[4];
    const float* mb     = (const float*)d_in[5];
    const float* cw     = (const float*)d_in[6];
    const float* w1     = (const float*)d_in[7];
    const float* b1     = (const float*)d_in[8];
    const float* w2     = (const float*)d_in[9];
    const float* b2     = (const float*)d_in[10];
    float* out = (float*)d_out;

    char* ws = (char*)d_ws;
    ushort* anc_g  = (ushort*)(ws);                    // 8,388,608 B
    ushort* xcat_g = (ushort*)(ws + 8388608);          // 8,388,608 B
    char*   wsm    = ws + 16777216;
    ushort* rw1p   = (ushort*)(wsm);                   // 147,456 B
    ushort* rw2p   = (ushort*)(wsm + 147456);          // 73,728 B
    ushort* rpwh   = (ushort*)(wsm + 147456 + 73728);             // 49,152 B
    ushort* rpwl   = (ushort*)(wsm + 147456 + 73728 + 49152);     // 49,152 B
    ushort* rcwp   = (ushort*)(wsm + 147456 + 73728 + 98304);     // 24,576 B

    prep<<<800, 256, 0, stream>>>(anchor, w1, w2, pw, pb, mw, mb, cw,
                                  anc_g, rw1p, rw2p, rpwh, rpwl, rcwp);
    deform_mfma<<<dim3(64, 8, 4), 256, 0, stream>>>(o, anc_g, rpwh, rpwl, rcwp,
                                                    xcat_g);
    conv12_mfma<<<dim3(128, 4), 256, 0, stream>>>(xcat_g, anc_g, rw1p, b1,
                                                  rw2p, b2, out);
}

// Round 14
// 164.041 us; speedup vs baseline: 1.0808x; 1.0808x over previous
//
#include <hip/hip_runtime.h>

// ============================================================================
// MotionCompensation on MI355X — round 14: composite of measured-best pieces.
//  - prep: r10 split (anchor transform 32ch/block, 800 blocks)
//  - deform: r12 (31.7 KB LDS overlay, launch_bounds(256,4), no spills)
//  - conv12: r9 VERBATIM (16x8 patch, stride 72, two-phase staging) — the
//    fastest conv12 measured (<=43.5 us); stride-76/134 "bank fixes" both
//    regressed it (47/51 us) — conflicts were only ~4 us, not the limiter.
// ============================================================================

typedef __attribute__((ext_vector_type(8))) short short8;
typedef __attribute__((ext_vector_type(4))) float float4v;
typedef __attribute__((ext_vector_type(2))) float float2v;

#define MFMA_B16(a, b, c) __builtin_amdgcn_mfma_f32_16x16x32_bf16(a, b, c, 0, 0, 0)

__device__ __forceinline__ ushort f2bf(float f) {          // RNE f32 -> bf16
    union { float f; unsigned u; } v; v.f = f;
    unsigned r = v.u + 0x7FFFu + ((v.u >> 16) & 1u);
    return (ushort)(r >> 16);
}
__device__ __forceinline__ float bf2f(ushort h) {
    union { unsigned u; float f; } v; v.u = ((unsigned)h) << 16;
    return v.f;
}

// weights+offsets for one deformable tap (4 corners)
__device__ __forceinline__ void tap_wo(int gy, int gx, int n,
                                       float ox, float oy, float mzv,
                                       float* W, int* O)
{
    int ky = n / 3, kx = n - ky * 3;
    float pxf = (float)(gy + ky) + ox;
    float pyf = (float)(gx + kx) + oy;
    float fx = floorf(pxf), fy = floorf(pyf);
    float qxl = fminf(fmaxf(fx, 0.f), 127.f);
    float qxr = fminf(fmaxf(fx + 1.f, 0.f), 127.f);
    float qyl = fminf(fmaxf(fy, 0.f), 127.f);
    float qyr = fminf(fmaxf(fy + 1.f, 0.f), 127.f);
    float pxc = fminf(fmaxf(pxf, 0.f), 127.f);
    float pyc = fminf(fmaxf(pyf, 0.f), 127.f);
    float glx = 1.f + (qxl - pxc), grx = 1.f - (qxr - pxc);
    float gly = 1.f + (qyl - pyc), gry = 1.f - (qyr - pyc);
    float mm = 1.f / (1.f + __expf(-mzv));
    W[0] = glx * gly * mm; W[1] = grx * gry * mm;
    W[2] = glx * gry * mm; W[3] = grx * gly * mm;
    int ixl = (int)qxl, ixr = (int)qxr, iyl = (int)qyl, iyr = (int)qyr;
    O[0] = ixl * 128 + iyl; O[1] = ixr * 128 + iyr;
    O[2] = ixl * 128 + iyr; O[3] = ixr * 128 + iyl;
}

// packed-float2 bilinear blend of 4 corner short8s; bf16 pack via v_perm
__device__ __forceinline__ short8 interp4(const float* W, const short8* cv)
{
    union U { short8 s; uint4 u; };
    uint4 c[4];
    #pragma unroll
    for (int j = 0; j < 4; ++j) { U t; t.s = cv[j]; c[j] = t.u; }
    U out;
    #pragma unroll
    for (int p = 0; p < 4; ++p) {       // channel pair p = (2p, 2p+1)
        float2v acc = {0.f, 0.f};
        #pragma unroll
        for (int j = 0; j < 4; ++j) {
            unsigned d = (&c[j].x)[p];
            float2v cc = {__uint_as_float(d << 16),
                          __uint_as_float(d & 0xffff0000u)};
            float2v Wv = {W[j], W[j]};
            acc = __builtin_elementwise_fma(cc, Wv, acc);
        }
        unsigned u0 = __float_as_uint(acc.x), u1 = __float_as_uint(acc.y);
        (&out.u.x)[p] = __builtin_amdgcn_perm(u1, u0, 0x07060302u);  // trunc pack
    }
    return out.s;
}

// ---------------------------------------------------------------------------
// prep: blocks 0..511: anchor NCHW f32 -> grouped bf16 (32 ch per block);
//       blocks 512..799: weight repack into wave-coalesced frag layouts:
//   rw1x[s9][ks4][oc64][kk32]   rw2x[s9][ks2][oc64][kk32]
//   rpwx[g8][ks3][n32][kk32] hi/lo  (k=ks*32+kk; k<72: s=k>>3,ic=k&7; k==72 bias)
//   rcwx[g8][ks3][oc16][kk32]       (k<72: n=k>>3, ic=k&7)
// ---------------------------------------------------------------------------
__global__ __launch_bounds__(256) void prep(
    const float* __restrict__ anchor,
    const float* __restrict__ w1, const float* __restrict__ w2,
    const float* __restrict__ pw, const float* __restrict__ pb,
    const float* __restrict__ mw, const float* __restrict__ mb,
    const float* __restrict__ cw,
    ushort* __restrict__ anc_g,
    ushort* __restrict__ rw1, ushort* __restrict__ rw2,
    ushort* __restrict__ rpwh, ushort* __restrict__ rpwl,
    ushort* __restrict__ rcw)
{
    const int blk = blockIdx.x;
    if (blk < 512) {                       // ---- anchor transform (32 ch/blk)
        int pix = (blk & 63) * 256 + threadIdx.x;
        int b = (blk >> 6) & 3;
        int half = blk >> 8;               // 0: ch 0-31, 1: ch 32-63
        ushort tmp[32];
        #pragma unroll
        for (int ch = 0; ch < 32; ++ch)
            tmp[ch] = f2bf(anchor[(((size_t)(b * 64 + half * 32 + ch)) << 14) + pix]);
        #pragma unroll
        for (int grp = 0; grp < 4; ++grp) {
            short8 v;
            #pragma unroll
            for (int j = 0; j < 8; ++j) v[j] = (short)tmp[grp * 8 + j];
            *(short8*)(anc_g + ((size_t)(b * 8 + half * 4 + grp)) * 131072
                       + (size_t)pix * 8) = v;
        }
        return;
    }
    int i = (blk - 512) * 256 + threadIdx.x;   // ---- repack
    if (i < 73728) {                       // rw1x
        int kk = i & 31, r = i >> 5, oc = r & 63, r2 = r >> 6;
        int ks = r2 & 3, s = r2 >> 2, ic = ks * 32 + kk;
        rw1[i] = f2bf(w1[(oc * 128 + ic) * 9 + s]);
    }
    if (i < 36864) {                       // rw2x
        int kk = i & 31, r = i >> 5, oc = r & 63, r2 = r >> 6;
        int ks = r2 & 1, s = r2 >> 1, ic = ks * 32 + kk;
        rw2[i] = f2bf(w2[(oc * 64 + ic) * 9 + s]);
    }
    if (i < 24576) {                       // rpwx hi/lo
        int kk = i & 31, r = i >> 5, n = r & 31, r2 = r >> 5;
        int ks = r2 % 3, g = r2 / 3, k = ks * 32 + kk;
        float v = 0.f;
        if (k < 72) {
            int s = k >> 3, ic = k & 7;
            if (n < 18)      v = pw[((g * 18 + n) * 8 + ic) * 9 + s];
            else if (n < 27) v = mw[((g * 9 + (n - 18)) * 8 + ic) * 9 + s];
        } else if (k == 72) {
            if (n < 18)      v = pb[g * 18 + n];
            else if (n < 27) v = mb[g * 9 + (n - 18)];
        }
        ushort h = f2bf(v);
        rpwh[i] = h;
        rpwl[i] = f2bf(v - bf2f(h));
    }
    if (i < 12288) {                       // rcwx
        int kk = i & 31, r = i >> 5, oc = r & 15, r2 = r >> 4;
        int ks = r2 % 3, g = r2 / 3, k = ks * 32 + kk;
        float v = 0.f;
        if (k < 72 && oc < 8) {
            int n = k >> 3, ic = k & 7;
            v = cw[((g * 8 + oc) * 8 + ic) * 9 + n];
        }
        rcw[i] = f2bf(v);
    }
}

// ---------------------------------------------------------------------------
// Deformable stage (r12). LDS 31,744 B, launch bounds (256,4): no spills,
// LDS-limited 5 blocks/CU. sOff overlays dead slab after barrier 2.
// ---------------------------------------------------------------------------
__global__ __launch_bounds__(256, 4) void deform_mfma(
    const float* __restrict__ o, const ushort* __restrict__ anc_g,
    const ushort* __restrict__ rpwh, const ushort* __restrict__ rpwl,
    const ushort* __restrict__ rcw,
    ushort* __restrict__ xcat_g)
{
    const int tile = blockIdx.x, g = blockIdx.y, b = blockIdx.z;
    const int ty0 = (tile >> 3) * 16, tx0 = (tile & 7) * 16;
    const int tid = threadIdx.x, lane = tid & 63, wave = tid >> 6;
    const int l15 = lane & 15, quad = lane >> 4;

    __shared__ __align__(16) ushort sU[15872];        // 31,744 B
    ushort* slabh = sU;                               // [0, 5184)
    ushort* slabl = sU + 2592;                        // [5184, 10368)
    float*  sOff  = (float*)sU;                       // [0, 27648) after barrier 2
    ushort* sEu   = sU + 13824;                       // [27648, 31744)

    const float* obase = o + (((size_t)(b * 64 + g * 8)) << 14);
    #pragma unroll
    for (int pass = 0; pass < 2; ++pass) {
        int pix = tid + pass * 256;
        if (pix < 324) {
            int r = pix / 18, c = pix - r * 18;
            int gy = ty0 + r - 1, gx = tx0 + c - 1;
            short8 vh = {0, 0, 0, 0, 0, 0, 0, 0};
            short8 vl = {0, 0, 0, 0, 0, 0, 0, 0};
            if ((unsigned)gy < 128u && (unsigned)gx < 128u) {
                const float* p0 = obase + (gy << 7) + gx;
                #pragma unroll
                for (int ic = 0; ic < 8; ++ic) {
                    float v = p0[(size_t)ic << 14];
                    ushort h = f2bf(v);
                    vh[ic] = (short)h;
                    vl[ic] = (short)f2bf(v - bf2f(h));
                }
            }
            *(short8*)(&slabh[pix * 8]) = vh;
            *(short8*)(&slabl[pix * 8]) = vl;
        }
    }
    __syncthreads();                                  // barrier 1

    // ---- phase A: offset/mask conv, split-bf16 3-MFMA
    float4v offacc[4][2] = {};
    #pragma unroll
    for (int ks = 0; ks < 3; ++ks) {
        short8 Bh[2], Bl[2];
        #pragma unroll
        for (int nf = 0; nf < 2; ++nf) {
            int off = ((g * 3 + ks) * 32 + nf * 16 + l15) * 32 + quad * 8;
            Bh[nf] = *(const short8*)(rpwh + off);
            Bl[nf] = *(const short8*)(rpwl + off);
        }
        short8 Ah[4], Al[4];
        if (ks < 2) {
            int s = ks * 4 + quad, sy = s / 3, sx = s - sy * 3;
            #pragma unroll
            for (int py = 0; py < 4; ++py) {
                int row = wave * 4 + py;
                int sl = ((row + sy) * 18 + l15 + sx) * 8;
                Ah[py] = *(const short8*)(&slabh[sl]);
                Al[py] = *(const short8*)(&slabl[sl]);
            }
        } else {
            #pragma unroll
            for (int py = 0; py < 4; ++py) {
                short8 zh = {0, 0, 0, 0, 0, 0, 0, 0};
                short8 zl = {0, 0, 0, 0, 0, 0, 0, 0};
                if (quad == 0) {
                    int row = wave * 4 + py;
                    int sl = ((row + 2) * 18 + l15 + 2) * 8;
                    zh = *(const short8*)(&slabh[sl]);
                    zl = *(const short8*)(&slabl[sl]);
                } else if (quad == 1) {
                    zh[0] = (short)0x3F80;
                }
                Ah[py] = zh; Al[py] = zl;
            }
        }
        #pragma unroll
        for (int py = 0; py < 4; ++py)
            #pragma unroll
            for (int nf = 0; nf < 2; ++nf) {
                offacc[py][nf] = MFMA_B16(Ah[py], Bh[nf], offacc[py][nf]);
                offacc[py][nf] = MFMA_B16(Ah[py], Bl[nf], offacc[py][nf]);
                offacc[py][nf] = MFMA_B16(Al[py], Bh[nf], offacc[py][nf]);
            }
    }
    // phase C B-frags (global, L2-hot) — load before the barrier
    short8 Bw[3];
    #pragma unroll
    for (int ks = 0; ks < 3; ++ks)
        Bw[ks] = *(const short8*)(rcw + (((g * 3 + ks) * 16 + l15) * 32 + quad * 8));

    __syncthreads();                                  // barrier 2: slab dead
    // D bounce (pxcol = quad*4+reg, ch = nf*16+l15) -> sOff (own-wave rows)
    #pragma unroll
    for (int py = 0; py < 4; ++py) {
        int p0 = (wave * 4 + py) * 16 + quad * 4;
        #pragma unroll
        for (int nf = 0; nf < 2; ++nf) {
            int ch = nf * 16 + l15;
            if (ch < 27) {
                #pragma unroll
                for (int reg = 0; reg < 4; ++reg)
                    sOff[(p0 + reg) * 27 + ch] = offacc[py][nf][reg];
            }
        }
    }
    // no barrier: everything below touches only this wave's rows

    const ushort* gb = anc_g + ((size_t)(b * 8 + g)) * 131072;
    const int n1 = quad, n2 = quad + 4;
    float4v cacc[4] = {};
    #pragma unroll
    for (int py = 0; py < 4; ++py) {
        int prow = wave * 4 + py;
        int p = prow * 16 + l15;
        int gy = ty0 + prow, gx = tx0 + l15;

        float W[8]; int O[8];
        tap_wo(gy, gx, n1, sOff[p * 27 + n1], sOff[p * 27 + 9 + n1],
               sOff[p * 27 + 18 + n1], &W[0], &O[0]);
        tap_wo(gy, gx, n2, sOff[p * 27 + n2], sOff[p * 27 + 9 + n2],
               sOff[p * 27 + 18 + n2], &W[4], &O[4]);
        short8 cv[8];
        #pragma unroll
        for (int j = 0; j < 8; ++j)
            cv[j] = *(const short8*)(gb + (size_t)O[j] * 8);
        short8 A0 = interp4(&W[0], &cv[0]);
        short8 A1 = interp4(&W[4], &cv[4]);
        short8 A2 = {0, 0, 0, 0, 0, 0, 0, 0};
        if (quad == 0) {
            float W2[4]; int O2[4];
            tap_wo(gy, gx, 8, sOff[p * 27 + 8], sOff[p * 27 + 17],
                   sOff[p * 27 + 26], W2, O2);
            short8 c2[4];
            #pragma unroll
            for (int j = 0; j < 4; ++j)
                c2[j] = *(const short8*)(gb + (size_t)O2[j] * 8);
            A2 = interp4(W2, c2);
        }
        cacc[py] = MFMA_B16(A0, Bw[0], cacc[py]);
        cacc[py] = MFMA_B16(A1, Bw[1], cacc[py]);
        cacc[py] = MFMA_B16(A2, Bw[2], cacc[py]);
    }

    // epilogue bounce (own-wave rows of sEu; no barrier needed)
    #pragma unroll
    for (int py = 0; py < 4; ++py) {
        if (l15 < 8) {
            #pragma unroll
            for (int reg = 0; reg < 4; ++reg)
                sEu[((wave * 4 + py) * 16 + quad * 4 + reg) * 8 + l15] =
                    f2bf(cacc[py][reg]);
        }
    }
    __builtin_amdgcn_s_waitcnt(0);                    // drain own LDS writes
    {
        const int gy = ty0 + (tid >> 4), gx = tx0 + (tid & 15);
        short8 pk = *(const short8*)(&sEu[tid * 8]);
        *(short8*)(xcat_g + ((size_t)(b * 8 + g)) * 131072
                   + (size_t)((gy << 7) + gx) * 8) = pk;
    }
}

// ---------------------------------------------------------------------------
// conv12 (r9 verbatim): fused conv1 (128->64, +b1) and conv2 (64->64, +b2,
// +residual). 16x8 output patch, LDS stride 72, two-phase staging; sT1
// overlays dead sA. Fastest measured conv12 (<=43.5 us).
// ---------------------------------------------------------------------------
__global__ __launch_bounds__(256, 2) void conv12_mfma(
    const ushort* __restrict__ xg, const ushort* __restrict__ ag,
    const ushort* __restrict__ rw1, const float* __restrict__ b1,
    const ushort* __restrict__ rw2, const float* __restrict__ b2,
    float* __restrict__ out)
{
    const int patch = blockIdx.x, b = blockIdx.y;
    const int px0 = (patch & 7) * 16, py0 = (patch >> 3) * 8;
    const int tid = threadIdx.x, lane = tid & 63, wave = tid >> 6;
    const int l15 = lane & 15, quad = lane >> 4;

    __shared__ __align__(16) ushort sA[240 * 72];     // 34,560 B; sT1 overlays

    // per-lane A-row geometry for conv1 M-tiles t = 3*wave + j
    int base[3];
    #pragma unroll
    for (int j = 0; j < 3; ++j) {
        int q = 48 * wave + 16 * j + l15;
        int qe = q < 180 ? q : 179;
        int r = qe / 18, c = qe - r * 18;
        base[j] = r * 20 + c;                          // I-region linear index
    }

    float4v acc1[3][4] = {};                           // [j][nf]
    #pragma unroll
    for (int ph = 0; ph < 2; ++ph) {
        if (ph) __syncthreads();                       // prior reads done
        const ushort* src = (ph == 0) ? xg : ag;
        if (tid < 240) {                               // stage I: 12x20 px, 8 planes
            int ri = tid / 20, ci = tid - ri * 20;
            int gy = py0 - 2 + ri, gx = px0 - 2 + ci;
            bool in = ((unsigned)gy < 128u) && ((unsigned)gx < 128u);
            size_t poff = (size_t)((gy << 7) + gx) * 8;
            #pragma unroll
            for (int grp = 0; grp < 8; ++grp) {
                short8 v = {0, 0, 0, 0, 0, 0, 0, 0};
                if (in)
                    v = *(const short8*)(src + ((size_t)(b * 8 + grp)) * 131072 + poff);
                *(short8*)(&sA[tid * 72 + grp * 8]) = v;
            }
        }
        __syncthreads();

        #pragma unroll
        for (int ks2 = 0; ks2 < 2; ++ks2) {
            const int ks = ph * 2 + ks2;
            #pragma unroll
            for (int s = 0; s < 9; ++s) {
                const int ky = s / 3, kx = s - ky * 3;
                short8 Bf[4];
                #pragma unroll
                for (int nf = 0; nf < 4; ++nf)
                    Bf[nf] = *(const short8*)(rw1 +
                        (((s * 4 + ks) * 64 + nf * 16 + l15) * 32 + quad * 8));
                #pragma unroll
                for (int j = 0; j < 3; ++j) {
                    short8 A = *(const short8*)(&sA[(base[j] + ky * 20 + kx) * 72
                                                    + ks2 * 32 + quad * 8]);
                    #pragma unroll
                    for (int nf = 0; nf < 4; ++nf)
                        acc1[j][nf] = MFMA_B16(A, Bf[nf], acc1[j][nf]);
                }
            }
        }
    }
    __syncthreads();                                   // sA dead -> sT1 overlay
    ushort* sT1 = sA;                                  // 180 rows x 72
    #pragma unroll
    for (int j = 0; j < 3; ++j) {
        #pragma unroll
        for (int reg = 0; reg < 4; ++reg) {
            int q = 48 * wave + 16 * j + quad * 4 + reg;
            int r = q / 18, c = q - r * 18;            // R-region coords
            int gy = py0 - 1 + r, gx = px0 - 1 + c;
            bool in = ((unsigned)gy < 128u) && ((unsigned)gx < 128u);
            #pragma unroll
            for (int nf = 0; nf < 4; ++nf) {
                int oc = nf * 16 + l15;
                float v = acc1[j][nf][reg] + b1[oc];
                sT1[q * 72 + oc] = in ? f2bf(v) : (ushort)0;
            }
        }
    }
    __syncthreads();

    // ---- conv2 from sT1; wave w owns oc tile [16w, 16w+16)
    float4v acc2[8] = {};
    #pragma unroll
    for (int ks = 0; ks < 2; ++ks) {
        #pragma unroll
        for (int s = 0; s < 9; ++s) {
            const int ky = s / 3, kx = s - ky * 3;
            short8 Aw = *(const short8*)(rw2 +
                (((s * 2 + ks) * 64 + wave * 16 + l15) * 32 + quad * 8));
            #pragma unroll
            for (int f = 0; f < 8; ++f) {
                int q = (f + ky) * 18 + l15 + kx;
                short8 Bx = *(const short8*)(&sT1[q * 72 + ks * 32 + quad * 8]);
                acc2[f] = MFMA_B16(Aw, Bx, acc2[f]);
            }
        }
    }
    // epilogue: D oc = 16*wave + quad*4+reg, px = (f, l15); +b2 +residual
    #pragma unroll
    for (int f = 0; f < 8; ++f) {
        int gy = py0 + f, gx = px0 + l15;
        int pix = (gy << 7) + gx;
        #pragma unroll
        for (int reg = 0; reg < 4; ++reg) {
            int oc = wave * 16 + quad * 4 + reg;
            float res = bf2f(xg[((size_t)(b * 8 + (oc >> 3))) * 131072
                               + (size_t)pix * 8 + (oc & 7)]);
            out[(((size_t)(b * 64 + oc)) << 14) + pix] = acc2[f][reg] + b2[oc] + res;
        }
    }
}

// ---------------------------------------------------------------------------
extern "C" void kernel_launch(void* const* d_in, const int* in_sizes, int n_in,
                              void* d_out, int out_size, void* d_ws, size_t ws_size,
                              hipStream_t stream) {
    const float* o      = (const float*)d_in[0];
    const float* anchor = (const float*)d_in[1];
    const float* pw     = (const float*)d_in[2];
    const float* pb     = (const float*)d_in[3];
    const float* mw     = (const float*)d_in[4];
    const float* mb     = (const float*)d_in[5];
    const float* cw     = (const float*)d_in[6];
    const float* w1     = (const float*)d_in[7];
    const float* b1     = (const float*)d_in[8];
    const float* w2     = (const float*)d_in[9];
    const float* b2     = (const float*)d_in[10];
    float* out = (float*)d_out;

    char* ws = (char*)d_ws;
    ushort* anc_g  = (ushort*)(ws);                    // 8,388,608 B
    ushort* xcat_g = (ushort*)(ws + 8388608);          // 8,388,608 B
    char*   wsm    = ws + 16777216;
    ushort* rw1p   = (ushort*)(wsm);                   // 147,456 B
    ushort* rw2p   = (ushort*)(wsm + 147456);          // 73,728 B
    ushort* rpwh   = (ushort*)(wsm + 147456 + 73728);             // 49,152 B
    ushort* rpwl   = (ushort*)(wsm + 147456 + 73728 + 49152);     // 49,152 B
    ushort* rcwp   = (ushort*)(wsm + 147456 + 73728 + 98304);     // 24,576 B

    prep<<<800, 256, 0, stream>>>(anchor, w1, w2, pw, pb, mw, mb, cw,
                                  anc_g, rw1p, rw2p, rpwh, rpwl, rcwp);
    deform_mfma<<<dim3(64, 8, 4), 256, 0, stream>>>(o, anc_g, rpwh, rpwl, rcwp,
                                                    xcat_g);
    conv12_mfma<<<dim3(128, 4), 256, 0, stream>>>(xcat_g, anc_g, rw1p, b1,
                                                  rw2p, b2, out);
}